// Round 15
// baseline (198.576 us; speedup 1.0000x reference)
//
#include <hip/hip_runtime.h>
#include <hip/hip_bf16.h>

#define S 1024
#define D 64
#define BH 64
#define SCALE 0.125f

typedef __attribute__((ext_vector_type(8))) short short8;
typedef __attribute__((ext_vector_type(4))) short s4v;
typedef __attribute__((ext_vector_type(4))) int i4v;
typedef __attribute__((ext_vector_type(16))) float f32x16;

// fp32 -> bf16 RNE. Plain bit ops, NO inline asm (rounds 2-4 regression).
static __device__ __forceinline__ unsigned short f2bf(float f) {
  union { float f; unsigned u; } v; v.f = f;
  return (unsigned short)((v.u + 0x7fffu + ((v.u >> 16) & 1u)) >> 16);
}

static __device__ __forceinline__ float bf2f(unsigned short h) {
  union { unsigned u; float f; } v; v.u = (unsigned)h << 16; return v.f;
}

static __device__ __forceinline__ short8 load_frag8_f32(const float* p) {
  float4 a = *(const float4*)p;
  float4 b = *(const float4*)(p + 4);
  short8 r;
  r[0] = f2bf(a.x); r[1] = f2bf(a.y); r[2] = f2bf(a.z); r[3] = f2bf(a.w);
  r[4] = f2bf(b.x); r[5] = f2bf(b.y); r[6] = f2bf(b.z); r[7] = f2bf(b.w);
  return r;
}

// Merged pre-pass: y=0 -> q cvt, y=1 -> k cvt, y=2 -> v transpose to vT.
__global__ __launch_bounds__(256) void prep_kernel(
    const float* __restrict__ q, const float* __restrict__ k,
    const float* __restrict__ v, unsigned short* __restrict__ qbf,
    unsigned short* __restrict__ kbf, unsigned short* __restrict__ vt) {
  int tid = threadIdx.x;
  if (blockIdx.y < 2) {
    const float* s = blockIdx.y == 0 ? q : k;
    unsigned short* d = blockIdx.y == 0 ? qbf : kbf;
    size_t i = (size_t)(blockIdx.x * 256 + tid) * 8;
#pragma unroll
    for (int c = 0; c < 2; ++c, i += (size_t)1024 * 256 * 8)
      *(short8*)(d + i) = load_frag8_f32(s + i);
  } else {
    __shared__ float t[64][65];
    int bh = blockIdx.x >> 4;
    int s0 = (blockIdx.x & 15) * 64;
    {
      int r = tid >> 2, c4 = (tid & 3) * 16;
      const float4* src = (const float4*)(v + ((size_t)bh * S + s0 + r) * D + c4);
#pragma unroll
      for (int j = 0; j < 4; ++j) {
        float4 x = src[j];
        t[r][c4 + j * 4 + 0] = x.x; t[r][c4 + j * 4 + 1] = x.y;
        t[r][c4 + j * 4 + 2] = x.z; t[r][c4 + j * 4 + 3] = x.w;
      }
    }
    __syncthreads();
    {
      int d0 = tid >> 2, sc = (tid & 3) * 16;
      unsigned short* dst = vt + ((size_t)bh * D + d0) * S + s0 + sc;
      short8 o0, o1;
#pragma unroll
      for (int j = 0; j < 8; ++j) {
        o0[j] = (short)f2bf(t[sc + j][d0]);
        o1[j] = (short)f2bf(t[sc + 8 + j][d0]);
      }
      *(short8*)dst = o0;
      *(short8*)(dst + 8) = o1;
    }
  }
}

// Phase 1 (round-13 proven): block owns 128 q-rows of one bh; stream mask
// slice row-sequentially (NT int4), bit-pack; QK^T + exp -> column partials.
__global__ __launch_bounds__(256) void colsum2_kernel(
    const unsigned short* __restrict__ qbf, const unsigned short* __restrict__ kbf,
    const int* __restrict__ mask, unsigned* __restrict__ packed,
    float* __restrict__ partial) {
  int tid = threadIdx.x;
  int wave = tid >> 6, lane = tid & 63;
  int l31 = lane & 31, hi = lane >> 5;
  int d0 = blockIdx.x;
  int xcd = d0 & 7, idx = d0 >> 3;
  int bh = xcd * 8 + (idx >> 3);
  int qblk = idx & 7;
  int qb = qblk * 128;
  const int* mh = mask + ((size_t)bh * S + qb) * S;

  __shared__ unsigned pk[4][1024];

#pragma unroll
  for (int qw = 0; qw < 4; ++qw) {
    unsigned w0 = 0, w1 = 0, w2 = 0, w3 = 0;
    for (int r = 0; r < 32; ++r) {
      i4v m = __builtin_nontemporal_load(
          (const i4v*)(mh + (size_t)(qw * 32 + r) * S + tid * 4));
      w0 |= (m[0] != 0 ? 1u : 0u) << r;
      w1 |= (m[1] != 0 ? 1u : 0u) << r;
      w2 |= (m[2] != 0 ? 1u : 0u) << r;
      w3 |= (m[3] != 0 ? 1u : 0u) << r;
    }
    pk[qw][tid * 4 + 0] = w0; pk[qw][tid * 4 + 1] = w1;
    pk[qw][tid * 4 + 2] = w2; pk[qw][tid * 4 + 3] = w3;
  }
  __syncthreads();
  {
    const i4v* src = (const i4v*)&pk[0][0];
    i4v* dst = (i4v*)(packed + ((size_t)bh * 32 + qblk * 4) * S);
#pragma unroll
    for (int j = 0; j < 4; ++j) dst[tid + j * 256] = src[tid + j * 256];
  }

  short8 afrag[4];
  {
    const unsigned short* qp =
        qbf + ((size_t)bh * S + qb + wave * 32 + l31) * D + hi * 8;
#pragma unroll
    for (int s = 0; s < 4; ++s) afrag[s] = *(const short8*)(qp + s * 16);
  }
  const unsigned short* kbb = kbf + (size_t)bh * S * D;
  float* pout = partial + ((size_t)bh * 32 + qblk * 4 + wave) * S;

  for (int kt = 0; kt < 32; ++kt) {
    int kb2 = kt * 32;
    short8 bfrag[4];
    const unsigned short* kp = kbb + (size_t)(kb2 + l31) * D + hi * 8;
#pragma unroll
    for (int s = 0; s < 4; ++s) bfrag[s] = *(const short8*)(kp + s * 16);
    f32x16 acc = {};
#pragma unroll
    for (int s = 0; s < 4; ++s)
      acc = __builtin_amdgcn_mfma_f32_32x32x16_bf16(afrag[s], bfrag[s], acc, 0, 0, 0);

    unsigned mw = pk[wave][kb2 + l31];
    float cp = 0.f;
#pragma unroll
    for (int r = 0; r < 16; ++r) {
      int ql = (r & 3) + 8 * (r >> 2) + 4 * hi;
      cp += ((mw >> ql) & 1u) ? __expf(acc[r] * SCALE) : 0.0f;
    }
    cp += __shfl_xor(cp, 32, 64);
    if (lane < 32) pout[kb2 + lane] = cp;
  }
}

// rcp[bh][col] = 1 / sum of the 32 partials (deterministic order).
__global__ __launch_bounds__(256) void combine_kernel(
    const float* __restrict__ partial, float* __restrict__ rcp) {
  int g = blockIdx.x * 256 + threadIdx.x;
  int bh = g >> 10, col = g & 1023;
  float t = 0.f;
#pragma unroll
  for (int p = 0; p < 32; ++p)
    t += partial[((size_t)bh * 32 + p) * S + col];
  rcp[(size_t)bh * S + col] = 1.0f / t;
}

// Phase 2 v7: block = 32 q-rows x ALL 1024 cols (grid 2048). Waves sweep
// disjoint k-quarters barrier-free into block-shared ptb (column-disjoint);
// then ONE barrier and a write phase emitting fully-sequential 4KB rows
// (the 268MB attn stream at streaming DRAM efficiency). Block covers all k
// -> out complete per block (no combine/outp1). k/vT direct from L2/L3
// (2MB/XCD working set; refetch hits 256MB L3, not HBM), reg-dbuf prefetch.
__global__ __launch_bounds__(256, 2) void attn_out7_kernel(
    const unsigned short* __restrict__ qbf, const unsigned short* __restrict__ kbf,
    const unsigned short* __restrict__ vt, const unsigned* __restrict__ packed,
    const float* __restrict__ rcp, float* __restrict__ outp,
    float* __restrict__ attnp) {
  int tid = threadIdx.x;
  int wave = tid >> 6, lane = tid & 63;
  int l31 = lane & 31, hi = lane >> 5;
  int d0 = blockIdx.x;
  int xcd = d0 & 7, idx = d0 >> 3;
  int bh = xcd * 8 + (idx >> 5);   // 32 blocks/bh on one XCD
  int qblk = idx & 31;
  int qb = qblk * 32;
  const float* rch = rcp + (size_t)bh * S;
  float* ah = attnp + (size_t)bh * S * S;
  const unsigned short* vtb = vt + (size_t)bh * D * S;
  const unsigned short* kbb = kbf + (size_t)bh * S * D;
  const unsigned* pmw = packed + ((size_t)bh * 32 + qblk) * S;

  // 32 rows x 1024 cols bf16; stride 1036 keeps rows 8B-aligned (2072B)
  // with <=2-way banking on the PV b64 reads. 64.8 KB -> 2 blocks/CU.
  __shared__ unsigned short ptb[32][1036];

  // q fragments (rows qb..qb+31; identical across waves, L2-hot)
  short8 afrag[4];
  {
    const unsigned short* qp = qbf + ((size_t)bh * S + qb + l31) * D + hi * 8;
#pragma unroll
    for (int s = 0; s < 4; ++s) afrag[s] = *(const short8*)(qp + s * 16);
  }

  f32x16 oacc0 = {}, oacc1 = {};
  int kq = wave * 256;  // this wave's k-quarter (8 tiles)

  short8 kfr[2][4], vfr[2][4];
  unsigned mwreg[2];
  {
    const unsigned short* kp = kbb + (size_t)(kq + l31) * D + hi * 8;
#pragma unroll
    for (int s = 0; s < 4; ++s) kfr[0][s] = *(const short8*)(kp + s * 16);
    const unsigned short* vp = vtb + (size_t)l31 * S + kq + hi * 8;
    vfr[0][0] = *(const short8*)vp;
    vfr[0][1] = *(const short8*)(vp + (size_t)32 * S);
    vfr[0][2] = *(const short8*)(vp + 16);
    vfr[0][3] = *(const short8*)(vp + 16 + (size_t)32 * S);
    mwreg[0] = pmw[kq + l31];
  }

#pragma unroll
  for (int t = 0; t < 8; ++t) {
    const int cur = t & 1;   // compile-time under full unroll
    int kb2 = kq + t * 32;

    if (t < 7) {  // prefetch next tile into the other reg buffer
      const unsigned short* kp = kbb + (size_t)(kb2 + 32 + l31) * D + hi * 8;
#pragma unroll
      for (int s = 0; s < 4; ++s) kfr[cur ^ 1][s] = *(const short8*)(kp + s * 16);
      const unsigned short* vp = vtb + (size_t)l31 * S + kb2 + 32 + hi * 8;
      vfr[cur ^ 1][0] = *(const short8*)vp;
      vfr[cur ^ 1][1] = *(const short8*)(vp + (size_t)32 * S);
      vfr[cur ^ 1][2] = *(const short8*)(vp + 16);
      vfr[cur ^ 1][3] = *(const short8*)(vp + 16 + (size_t)32 * S);
      mwreg[cur ^ 1] = pmw[kb2 + 32 + l31];
    }

    f32x16 acc = {};
#pragma unroll
    for (int s = 0; s < 4; ++s)
      acc = __builtin_amdgcn_mfma_f32_32x32x16_bf16(afrag[s], kfr[cur][s], acc, 0, 0, 0);

    float rc = rch[kb2 + l31];
    unsigned mw = mwreg[cur];
#pragma unroll
    for (int r = 0; r < 16; ++r) {
      int ql = (r & 3) + 8 * (r >> 2) + 4 * hi;
      unsigned bit = (mw >> ql) & 1u;
      float e = bit ? __expf(acc[r] * SCALE) * rc : 0.0f;
      ptb[ql][kb2 + l31] = f2bf(e);
    }

    // PV: A from ptb row l31 (wave-local data), B from prefetched vT regs
#pragma unroll
    for (int s2 = 0; s2 < 2; ++s2) {
      const unsigned short* pp = &ptb[l31][kb2 + s2 * 16 + hi * 8];
      s4v p0 = *(const s4v*)pp;
      s4v p1 = *(const s4v*)(pp + 4);
      short8 pa;
      pa[0] = p0[0]; pa[1] = p0[1]; pa[2] = p0[2]; pa[3] = p0[3];
      pa[4] = p1[0]; pa[5] = p1[1]; pa[6] = p1[2]; pa[7] = p1[3];
      oacc0 = __builtin_amdgcn_mfma_f32_32x32x16_bf16(pa, vfr[cur][s2 * 2], oacc0, 0, 0, 0);
      oacc1 = __builtin_amdgcn_mfma_f32_32x32x16_bf16(pa, vfr[cur][s2 * 2 + 1], oacc1, 0, 0, 0);
    }
  }

  __syncthreads();  // all quarters of ptb complete

  // attn write: 32 fully-sequential 4KB rows (256 thr x 16B per row)
#pragma unroll 4
  for (int r = 0; r < 32; ++r) {
    s4v a = *(const s4v*)&ptb[r][tid * 4];
    float4 f;
    f.x = bf2f((unsigned short)a[0]); f.y = bf2f((unsigned short)a[1]);
    f.z = bf2f((unsigned short)a[2]); f.w = bf2f((unsigned short)a[3]);
    *(float4*)&ah[(size_t)(qb + r) * S + tid * 4] = f;
  }

  // out: 4-wave reduction through (reused) ptb, then single store
  __syncthreads();
  float* red = (float*)&ptb[0][0];  // need 3*2112*4 = 25.3 KB <= 64.8 KB
  if (wave > 0) {
    float* dst = red + (size_t)(wave - 1) * 2112 + lane * 33;
#pragma unroll
    for (int r = 0; r < 16; ++r) { dst[r] = oacc0[r]; dst[16 + r] = oacc1[r]; }
  }
  __syncthreads();
  if (wave == 0) {
#pragma unroll
    for (int w = 0; w < 3; ++w) {
      const float* src = red + (size_t)w * 2112 + lane * 33;
#pragma unroll
      for (int r = 0; r < 16; ++r) { oacc0[r] += src[r]; oacc1[r] += src[16 + r]; }
    }
    float* oh = outp + (size_t)bh * S * D;
#pragma unroll
    for (int r = 0; r < 16; ++r) {
      int ql = (r & 3) + 8 * (r >> 2) + 4 * hi;
      oh[(size_t)(qb + ql) * D + l31] = oacc0[r];
      oh[(size_t)(qb + ql) * D + 32 + l31] = oacc1[r];
    }
  }
}

// Fallback phase 1 (raw fp32, tiers 2/3).
template <bool PACK>
__global__ __launch_bounds__(256) void colsum_kernel(
    const float* __restrict__ q, const float* __restrict__ k,
    const int* __restrict__ mask, float* __restrict__ rcp,
    unsigned* __restrict__ packed) {
  int tid = threadIdx.x;
  int wave = tid >> 6, lane = tid & 63;
  int l31 = lane & 31, hi = lane >> 5;
  int d0 = blockIdx.x;
  int xcd = d0 & 7, idx = d0 >> 3;
  int bh = xcd * 8 + (idx >> 5);
  int kb = (idx & 31) * 32;
  const int* mh = mask + (size_t)bh * S * S;

  short8 bfrag[4];
  const float* kp = k + ((size_t)bh * S + kb + l31) * D + hi * 8;
#pragma unroll
  for (int s = 0; s < 4; ++s) bfrag[s] = load_frag8_f32(kp + s * 16);

  int kcol = kb + l31;
  float colpart = 0.f;
  for (int it = 0; it < 8; ++it) {
    int q0 = it * 128 + wave * 32;
    short8 afrag[4];
    const float* qp = q + ((size_t)bh * S + q0 + l31) * D + hi * 8;
#pragma unroll
    for (int s = 0; s < 4; ++s) afrag[s] = load_frag8_f32(qp + s * 16);
    f32x16 acc = {};
#pragma unroll
    for (int s = 0; s < 4; ++s)
      acc = __builtin_amdgcn_mfma_f32_32x32x16_bf16(afrag[s], bfrag[s], acc, 0, 0, 0);

    unsigned w = 0;
#pragma unroll
    for (int r = 0; r < 16; ++r) {
      int crow0 = (r & 3) + 8 * (r >> 2);
      int qrow = q0 + crow0 + 4 * hi;
      int m = __builtin_nontemporal_load(mh + (size_t)qrow * S + kcol);
      if (PACK) w |= (m ? 1u : 0u) << (crow0 + 4 * hi);
      colpart += m ? __expf(acc[r] * SCALE) : 0.0f;
    }
    if (PACK) {
      w |= __shfl_xor(w, 32, 64);
      if (lane < 32)
        packed[((size_t)bh * 32 + it * 4 + wave) * S + kb + l31] = w;
    }
  }
  colpart += __shfl_xor(colpart, 32, 64);
  __shared__ float red[4][32];
  if (lane < 32) red[wave][lane] = colpart;
  __syncthreads();
  if (tid < 32) {
    float t = red[0][tid] + red[1][tid] + red[2][tid] + red[3][tid];
    rcp[(size_t)bh * S + kb + tid] = 1.0f / t;
  }
}

// Fallback phase 2 (tiers 2/3).
template <bool PACKED>
__global__ __launch_bounds__(256) void attn_out_kernel(
    const float* __restrict__ q, const float* __restrict__ k,
    const float* __restrict__ v, const int* __restrict__ mask,
    const unsigned* __restrict__ packed, const float* __restrict__ rcp,
    float* __restrict__ outp, float* __restrict__ attnp) {
  int tid = threadIdx.x;
  int wave = tid >> 6, lane = tid & 63;
  int l31 = lane & 31, hi = lane >> 5;
  int bh = blockIdx.y;
  int qb = blockIdx.x * 128 + wave * 32;
  const int* mh = mask + (size_t)bh * S * S;
  const float* rch = rcp + (size_t)bh * S;
  float* ah = attnp + (size_t)bh * S * S;

  __shared__ float sm[4][32][33];
  __shared__ unsigned wlds[4][1024];

  if (PACKED) {
    const int4* src = (const int4*)(packed + ((size_t)bh * 32 + blockIdx.x * 4) * S);
    int4* dst = (int4*)&wlds[0][0];
#pragma unroll
    for (int j = 0; j < 4; ++j) dst[tid + j * 256] = src[tid + j * 256];
    __syncthreads();
  }

  short8 afrag[4];
  const float* qp = q + ((size_t)bh * S + qb + l31) * D + hi * 8;
#pragma unroll
  for (int s = 0; s < 4; ++s) afrag[s] = load_frag8_f32(qp + s * 16);

  f32x16 oacc0 = {}, oacc1 = {};

  for (int kt = 0; kt < 32; ++kt) {
    int kb2 = kt * 32;
    const float* kp = k + ((size_t)bh * S + kb2 + l31) * D + hi * 8;
    short8 bfrag[4];
#pragma unroll
    for (int s = 0; s < 4; ++s) bfrag[s] = load_frag8_f32(kp + s * 16);
    f32x16 acc = {};
#pragma unroll
    for (int s = 0; s < 4; ++s)
      acc = __builtin_amdgcn_mfma_f32_32x32x16_bf16(afrag[s], bfrag[s], acc, 0, 0, 0);

    int kcol = kb2 + l31;
    float rc = rch[kcol];
    unsigned mw = PACKED ? wlds[wave][kcol] : 0u;
#pragma unroll
    for (int r = 0; r < 16; ++r) {
      int ql = (r & 3) + 8 * (r >> 2) + 4 * hi;
      int qrow = qb + ql;
      unsigned bit;
      if (PACKED) bit = (mw >> ql) & 1u;
      else        bit = mh[(size_t)qrow * S + kcol] ? 1u : 0u;
      float e = bit ? __expf(acc[r] * SCALE) * rc : 0.0f;
      ah[(size_t)qrow * S + kcol] = e;
      sm[wave][ql][l31] = e;
    }
#pragma unroll
    for (int s2 = 0; s2 < 2; ++s2) {
      short8 pa;
      const float* smrow = &sm[wave][l31][0];
#pragma unroll
      for (int e = 0; e < 8; ++e) pa[e] = (short)f2bf(smrow[s2 * 16 + hi * 8 + e]);
      const float* vp = v + ((size_t)bh * S + kb2 + s2 * 16 + hi * 8) * D + l31;
      short8 vf0, vf1;
#pragma unroll
      for (int e = 0; e < 8; ++e) {
        vf0[e] = (short)f2bf(vp[(size_t)e * D]);
        vf1[e] = (short)f2bf(vp[(size_t)e * D + 32]);
      }
      oacc0 = __builtin_amdgcn_mfma_f32_32x32x16_bf16(pa, vf0, oacc0, 0, 0, 0);
      oacc1 = __builtin_amdgcn_mfma_f32_32x32x16_bf16(pa, vf1, oacc1, 0, 0, 0);
    }
  }

  float* oh = outp + (size_t)bh * S * D;
#pragma unroll
  for (int r = 0; r < 16; ++r) {
    int ql = (r & 3) + 8 * (r >> 2) + 4 * hi;
    oh[(size_t)(qb + ql) * D + l31] = oacc0[r];
    oh[(size_t)(qb + ql) * D + 32 + l31] = oacc1[r];
  }
}

extern "C" void kernel_launch(void* const* d_in, const int* in_sizes, int n_in,
                              void* d_out, int out_size, void* d_ws, size_t ws_size,
                              hipStream_t stream) {
  const float* q = (const float*)d_in[0];
  const float* k = (const float*)d_in[1];
  const float* v = (const float*)d_in[2];
  const int* mask = (const int*)d_in[3];
  float* outp = (float*)d_out;
  float* attnp = outp + (size_t)BH * S * D;  // out first, then attn
  float* rcp = (float*)d_ws;
  size_t rcp_bytes = (size_t)BH * S * 4;            // 256 KB
  size_t packed_bytes = (size_t)BH * 32 * S * 4;    // 8.4 MB
  size_t bf_bytes = (size_t)BH * S * D * 2;         // 8.4 MB each
  size_t partial_bytes = (size_t)BH * 32 * S * 4;   // 8.4 MB

  unsigned* packed = (unsigned*)((char*)d_ws + rcp_bytes);
  unsigned short* qbf = (unsigned short*)((char*)d_ws + rcp_bytes + packed_bytes);
  unsigned short* kbf = qbf + (size_t)BH * S * D;
  unsigned short* vt = kbf + (size_t)BH * S * D;
  float* partial = (float*)(vt + (size_t)BH * S * D);

  size_t need_t1 = rcp_bytes + packed_bytes + 3 * bf_bytes + partial_bytes;

  if (ws_size >= need_t1) {
    prep_kernel<<<dim3(1024, 3), 256, 0, stream>>>(q, k, v, qbf, kbf, vt);
    colsum2_kernel<<<512, 256, 0, stream>>>(qbf, kbf, mask, packed, partial);
    combine_kernel<<<256, 256, 0, stream>>>(partial, rcp);
    attn_out7_kernel<<<2048, 256, 0, stream>>>(qbf, kbf, vt, packed, rcp,
                                               outp, attnp);
  } else if (ws_size >= rcp_bytes + packed_bytes) {
    colsum_kernel<true><<<2048, 256, 0, stream>>>(q, k, mask, rcp, packed);
    attn_out_kernel<true><<<dim3(S / 128, BH), 256, 0, stream>>>(
        q, k, v, mask, packed, rcp, outp, attnp);
  } else {
    colsum_kernel<false><<<2048, 256, 0, stream>>>(q, k, mask, rcp, nullptr);
    attn_out_kernel<false><<<dim3(S / 128, BH), 256, 0, stream>>>(
        q, k, v, mask, nullptr, rcp, outp, attnp);
  }
}

// Round 16
// 178.826 us; speedup vs baseline: 1.1104x; 1.1104x over previous
//
#include <hip/hip_runtime.h>
#include <hip/hip_bf16.h>

#define S 1024
#define D 64
#define BH 64
#define SCALE 0.125f

typedef __attribute__((ext_vector_type(8))) short short8;
typedef __attribute__((ext_vector_type(4))) short s4v;
typedef __attribute__((ext_vector_type(4))) int i4v;
typedef __attribute__((ext_vector_type(16))) float f32x16;

// fp32 -> bf16 RNE. Plain bit ops, NO inline asm (rounds 2-4 regression).
static __device__ __forceinline__ unsigned short f2bf(float f) {
  union { float f; unsigned u; } v; v.f = f;
  return (unsigned short)((v.u + 0x7fffu + ((v.u >> 16) & 1u)) >> 16);
}

static __device__ __forceinline__ float bf2f(unsigned short h) {
  union { unsigned u; float f; } v; v.u = (unsigned)h << 16; return v.f;
}

static __device__ __forceinline__ short8 load_frag8_f32(const float* p) {
  float4 a = *(const float4*)p;
  float4 b = *(const float4*)(p + 4);
  short8 r;
  r[0] = f2bf(a.x); r[1] = f2bf(a.y); r[2] = f2bf(a.z); r[3] = f2bf(a.w);
  r[4] = f2bf(b.x); r[5] = f2bf(b.y); r[6] = f2bf(b.z); r[7] = f2bf(b.w);
  return r;
}

// Merged pre-pass: y=0 -> q cvt, y=1 -> k cvt, y=2 -> v transpose to vT.
__global__ __launch_bounds__(256) void prep_kernel(
    const float* __restrict__ q, const float* __restrict__ k,
    const float* __restrict__ v, unsigned short* __restrict__ qbf,
    unsigned short* __restrict__ kbf, unsigned short* __restrict__ vt) {
  int tid = threadIdx.x;
  if (blockIdx.y < 2) {
    const float* s = blockIdx.y == 0 ? q : k;
    unsigned short* d = blockIdx.y == 0 ? qbf : kbf;
    size_t i = (size_t)(blockIdx.x * 256 + tid) * 8;
#pragma unroll
    for (int c = 0; c < 2; ++c, i += (size_t)1024 * 256 * 8)
      *(short8*)(d + i) = load_frag8_f32(s + i);
  } else {
    __shared__ float t[64][65];
    int bh = blockIdx.x >> 4;
    int s0 = (blockIdx.x & 15) * 64;
    {
      int r = tid >> 2, c4 = (tid & 3) * 16;
      const float4* src = (const float4*)(v + ((size_t)bh * S + s0 + r) * D + c4);
#pragma unroll
      for (int j = 0; j < 4; ++j) {
        float4 x = src[j];
        t[r][c4 + j * 4 + 0] = x.x; t[r][c4 + j * 4 + 1] = x.y;
        t[r][c4 + j * 4 + 2] = x.z; t[r][c4 + j * 4 + 3] = x.w;
      }
    }
    __syncthreads();
    {
      int d0 = tid >> 2, sc = (tid & 3) * 16;
      unsigned short* dst = vt + ((size_t)bh * D + d0) * S + s0 + sc;
      short8 o0, o1;
#pragma unroll
      for (int j = 0; j < 8; ++j) {
        o0[j] = (short)f2bf(t[sc + j][d0]);
        o1[j] = (short)f2bf(t[sc + 8 + j][d0]);
      }
      *(short8*)dst = o0;
      *(short8*)(dst + 8) = o1;
    }
  }
}

// Phase 1 (round-13 proven): block owns 128 q-rows of one bh.
// Phase A: stream 512KB mask slice row-sequentially (NT int4), bit-pack to
// LDS + dump to packed[]. Phase B: QK^T, exp, per-wave column partials.
__global__ __launch_bounds__(256) void colsum2_kernel(
    const unsigned short* __restrict__ qbf, const unsigned short* __restrict__ kbf,
    const int* __restrict__ mask, unsigned* __restrict__ packed,
    float* __restrict__ partial) {
  int tid = threadIdx.x;
  int wave = tid >> 6, lane = tid & 63;
  int l31 = lane & 31, hi = lane >> 5;
  int d0 = blockIdx.x;
  int xcd = d0 & 7, idx = d0 >> 3;
  int bh = xcd * 8 + (idx >> 3);
  int qblk = idx & 7;
  int qb = qblk * 128;
  const int* mh = mask + ((size_t)bh * S + qb) * S;

  __shared__ unsigned pk[4][1024];

#pragma unroll
  for (int qw = 0; qw < 4; ++qw) {
    unsigned w0 = 0, w1 = 0, w2 = 0, w3 = 0;
    for (int r = 0; r < 32; ++r) {
      i4v m = __builtin_nontemporal_load(
          (const i4v*)(mh + (size_t)(qw * 32 + r) * S + tid * 4));
      w0 |= (m[0] != 0 ? 1u : 0u) << r;
      w1 |= (m[1] != 0 ? 1u : 0u) << r;
      w2 |= (m[2] != 0 ? 1u : 0u) << r;
      w3 |= (m[3] != 0 ? 1u : 0u) << r;
    }
    pk[qw][tid * 4 + 0] = w0; pk[qw][tid * 4 + 1] = w1;
    pk[qw][tid * 4 + 2] = w2; pk[qw][tid * 4 + 3] = w3;
  }
  __syncthreads();
  {
    const i4v* src = (const i4v*)&pk[0][0];
    i4v* dst = (i4v*)(packed + ((size_t)bh * 32 + qblk * 4) * S);
#pragma unroll
    for (int j = 0; j < 4; ++j) dst[tid + j * 256] = src[tid + j * 256];
  }

  short8 afrag[4];
  {
    const unsigned short* qp =
        qbf + ((size_t)bh * S + qb + wave * 32 + l31) * D + hi * 8;
#pragma unroll
    for (int s = 0; s < 4; ++s) afrag[s] = *(const short8*)(qp + s * 16);
  }
  const unsigned short* kbb = kbf + (size_t)bh * S * D;
  float* pout = partial + ((size_t)bh * 32 + qblk * 4 + wave) * S;

  for (int kt = 0; kt < 32; ++kt) {
    int kb2 = kt * 32;
    short8 bfrag[4];
    const unsigned short* kp = kbb + (size_t)(kb2 + l31) * D + hi * 8;
#pragma unroll
    for (int s = 0; s < 4; ++s) bfrag[s] = *(const short8*)(kp + s * 16);
    f32x16 acc = {};
#pragma unroll
    for (int s = 0; s < 4; ++s)
      acc = __builtin_amdgcn_mfma_f32_32x32x16_bf16(afrag[s], bfrag[s], acc, 0, 0, 0);

    unsigned mw = pk[wave][kb2 + l31];
    float cp = 0.f;
#pragma unroll
    for (int r = 0; r < 16; ++r) {
      int ql = (r & 3) + 8 * (r >> 2) + 4 * hi;
      cp += ((mw >> ql) & 1u) ? __expf(acc[r] * SCALE) : 0.0f;
    }
    cp += __shfl_xor(cp, 32, 64);
    if (lane < 32) pout[kb2 + lane] = cp;
  }
}

// rcp combine (tier-2 only)
__global__ __launch_bounds__(256) void combine_kernel(
    const float* __restrict__ partial, float* __restrict__ rcp) {
  int g = blockIdx.x * 256 + threadIdx.x;
  int bh = g >> 10, col = g & 1023;
  float t = 0.f;
#pragma unroll
  for (int p = 0; p < 32; ++p)
    t += partial[((size_t)bh * 32 + p) * S + col];
  rcp[(size_t)bh * S + col] = 1.0f / t;
}

// Phase 2 v6 (round-14 measured best): k-split across blocks. Grid 1024,
// XCD-swizzled: block = (bh, qblk, khalf); 4 waves x 128 q-rows x 16
// k-tiles. LDS 38.9KB -> 4 blocks/CU; rcp reduced from partial[] in the
// prologue; out -> outp (khalf 0) / outp1 (khalf 1), combined after.
__global__ __launch_bounds__(256, 4) void attn_out6_kernel(
    const unsigned short* __restrict__ qbf, const unsigned short* __restrict__ kbf,
    const unsigned short* __restrict__ vt, const unsigned* __restrict__ packed,
    const float* __restrict__ partial, float* __restrict__ outp,
    float* __restrict__ outp1, float* __restrict__ attnp) {
  int tid = threadIdx.x;
  int wave = tid >> 6, lane = tid & 63;
  int l31 = lane & 31, hi = lane >> 5;
  int d0 = blockIdx.x;
  int xcd = d0 & 7, idx = d0 >> 3;
  int bh = xcd * 8 + (idx >> 4);     // 16 blocks per bh on one XCD
  int sub = idx & 15;
  int qblk = sub >> 1, khalf = sub & 1;
  int qb = qblk * 128 + wave * 32;
  int koff = khalf * 512;
  float* ah = attnp + (size_t)bh * S * S;
  const unsigned short* vtb = vt + (size_t)bh * D * S;
  const unsigned short* kbb = kbf + (size_t)bh * S * D;
  const unsigned* pmwf = packed + ((size_t)bh * 32 + qblk * 4 + wave) * S;

  __shared__ unsigned short kst[2][32][72];   // 9.2 KB
  __shared__ unsigned short vst[2][64][40];   // 10.2 KB
  __shared__ unsigned short pt[4][32][68];    // 17.4 KB (2-tile groups)
  __shared__ float rcpl[512];                 // 2 KB -> total 38.9 KB

  int tr3 = tid >> 3, tc8 = tid & 7;
  int vr2 = tid >> 2, vc4 = tid & 3;

  // prologue: rcp for this k-half's 512 columns (partial[] is L2-hot)
  {
    float s0 = 0.f, s1 = 0.f;
    const float* pb = partial + (size_t)bh * 32 * S + koff;
    for (int p = 0; p < 32; ++p) {
      float2 f2 = *(const float2*)(pb + (size_t)p * S + tid * 2);
      s0 += f2.x; s1 += f2.y;
    }
    rcpl[tid * 2] = 1.0f / s0;
    rcpl[tid * 2 + 1] = 1.0f / s1;
  }

  // stage tile 0 (absolute k columns koff..koff+31)
  short8 kreg = *(const short8*)(kbb + (size_t)(koff + tr3) * D + tc8 * 8);
  short8 vreg = *(const short8*)(vtb + (size_t)vr2 * S + koff + vc4 * 8);
  unsigned mwcur = pmwf[koff + l31];
  short8 afrag[4];
  {
    const unsigned short* qp = qbf + ((size_t)bh * S + qb + l31) * D + hi * 8;
#pragma unroll
    for (int s = 0; s < 4; ++s) afrag[s] = *(const short8*)(qp + s * 16);
  }
  *(short8*)&kst[0][tr3][tc8 * 8] = kreg;
  *(short8*)&vst[0][vr2][vc4 * 8] = vreg;
  __syncthreads();

  f32x16 oacc0 = {}, oacc1 = {};

  for (int g = 0; g < 8; ++g) {
#pragma unroll
    for (int tg = 0; tg < 2; ++tg) {
      int ktl = g * 2 + tg;            // local tile 0..15
      int kb2 = koff + ktl * 32;       // absolute col base
      const int cur = tg;              // compile-time buffer index

      unsigned mwnxt = 0;
      if (ktl < 15) {
        kreg = *(const short8*)(kbb + (size_t)(kb2 + 32 + tr3) * D + tc8 * 8);
        vreg = *(const short8*)(vtb + (size_t)vr2 * S + kb2 + 32 + vc4 * 8);
        mwnxt = pmwf[kb2 + 32 + l31];
      }

      short8 bfrag[4];
#pragma unroll
      for (int s = 0; s < 4; ++s)
        bfrag[s] = *(const short8*)&kst[cur][l31][hi * 8 + s * 16];
      f32x16 acc = {};
#pragma unroll
      for (int s = 0; s < 4; ++s)
        acc = __builtin_amdgcn_mfma_f32_32x32x16_bf16(afrag[s], bfrag[s], acc, 0, 0, 0);

      short8 vA0 = *(const short8*)&vst[cur][l31][hi * 8];
      short8 vA1 = *(const short8*)&vst[cur][l31 + 32][hi * 8];
      short8 vB0 = *(const short8*)&vst[cur][l31][16 + hi * 8];
      short8 vB1 = *(const short8*)&vst[cur][l31 + 32][16 + hi * 8];

      float rc = rcpl[ktl * 32 + l31];
#pragma unroll
      for (int r = 0; r < 16; ++r) {
        int ql = (r & 3) + 8 * (r >> 2) + 4 * hi;
        unsigned bit = (mwcur >> ql) & 1u;
        float e = bit ? __expf(acc[r] * SCALE) * rc : 0.0f;
        pt[wave][ql][tg * 32 + l31] = f2bf(e);
      }
      mwcur = mwnxt;

#pragma unroll
      for (int s2 = 0; s2 < 2; ++s2) {
        const unsigned short* pp = &pt[wave][l31][tg * 32 + s2 * 16 + hi * 8];
        s4v p0 = *(const s4v*)pp;
        s4v p1 = *(const s4v*)(pp + 4);
        short8 pa;
        pa[0] = p0[0]; pa[1] = p0[1]; pa[2] = p0[2]; pa[3] = p0[3];
        pa[4] = p1[0]; pa[5] = p1[1]; pa[6] = p1[2]; pa[7] = p1[3];
        oacc0 = __builtin_amdgcn_mfma_f32_32x32x16_bf16(pa, s2 ? vB0 : vA0, oacc0, 0, 0, 0);
        oacc1 = __builtin_amdgcn_mfma_f32_32x32x16_bf16(pa, s2 ? vB1 : vA1, oacc1, 0, 0, 0);
      }

      if (ktl < 15) {
        *(short8*)&kst[cur ^ 1][tr3][tc8 * 8] = kreg;
        *(short8*)&vst[cur ^ 1][vr2][vc4 * 8] = vreg;
      }
      __syncthreads();
    }

    // attn write phase for group g: 32 rows x 256B contiguous runs.
#pragma unroll
    for (int it = 0; it < 8; ++it) {
      int row = it * 4 + (lane >> 4);
      int seg = lane & 15;
      const unsigned short* pp = &pt[wave][row][seg * 4];
      s4v a = *(const s4v*)pp;
      float4 f0;
      f0.x = bf2f((unsigned short)a[0]); f0.y = bf2f((unsigned short)a[1]);
      f0.z = bf2f((unsigned short)a[2]); f0.w = bf2f((unsigned short)a[3]);
      float* dst = &ah[(size_t)(qb + row) * S + koff + g * 64 + seg * 4];
      *(float4*)dst = f0;
    }
  }

  float* oh = (khalf ? outp1 : outp) + (size_t)bh * S * D;
#pragma unroll
  for (int r = 0; r < 16; ++r) {
    int ql = (r & 3) + 8 * (r >> 2) + 4 * hi;
    oh[(size_t)(qb + ql) * D + l31] = oacc0[r];
    oh[(size_t)(qb + ql) * D + 32 + l31] = oacc1[r];
  }
}

// out = out + out_partial1 (4.2M floats, float4 per thread)
__global__ __launch_bounds__(256) void combine_out_kernel(
    const float* __restrict__ p1, float* __restrict__ outp) {
  size_t i = ((size_t)blockIdx.x * 256 + threadIdx.x) * 4;
  float4 a = *(const float4*)(outp + i);
  float4 b = *(const float4*)(p1 + i);
  a.x += b.x; a.y += b.y; a.z += b.z; a.w += b.w;
  *(float4*)(outp + i) = a;
}

// Fallback phase 1 (raw fp32, tiers 3/4).
template <bool PACK>
__global__ __launch_bounds__(256) void colsum_kernel(
    const float* __restrict__ q, const float* __restrict__ k,
    const int* __restrict__ mask, float* __restrict__ rcp,
    unsigned* __restrict__ packed) {
  int tid = threadIdx.x;
  int wave = tid >> 6, lane = tid & 63;
  int l31 = lane & 31, hi = lane >> 5;
  int d0 = blockIdx.x;
  int xcd = d0 & 7, idx = d0 >> 3;
  int bh = xcd * 8 + (idx >> 5);
  int kb = (idx & 31) * 32;
  const int* mh = mask + (size_t)bh * S * S;

  short8 bfrag[4];
  const float* kp = k + ((size_t)bh * S + kb + l31) * D + hi * 8;
#pragma unroll
  for (int s = 0; s < 4; ++s) bfrag[s] = load_frag8_f32(kp + s * 16);

  int kcol = kb + l31;
  float colpart = 0.f;
  for (int it = 0; it < 8; ++it) {
    int q0 = it * 128 + wave * 32;
    short8 afrag[4];
    const float* qp = q + ((size_t)bh * S + q0 + l31) * D + hi * 8;
#pragma unroll
    for (int s = 0; s < 4; ++s) afrag[s] = load_frag8_f32(qp + s * 16);
    f32x16 acc = {};
#pragma unroll
    for (int s = 0; s < 4; ++s)
      acc = __builtin_amdgcn_mfma_f32_32x32x16_bf16(afrag[s], bfrag[s], acc, 0, 0, 0);

    unsigned w = 0;
#pragma unroll
    for (int r = 0; r < 16; ++r) {
      int crow0 = (r & 3) + 8 * (r >> 2);
      int qrow = q0 + crow0 + 4 * hi;
      int m = __builtin_nontemporal_load(mh + (size_t)qrow * S + kcol);
      if (PACK) w |= (m ? 1u : 0u) << (crow0 + 4 * hi);
      colpart += m ? __expf(acc[r] * SCALE) : 0.0f;
    }
    if (PACK) {
      w |= __shfl_xor(w, 32, 64);
      if (lane < 32)
        packed[((size_t)bh * 32 + it * 4 + wave) * S + kb + l31] = w;
    }
  }
  colpart += __shfl_xor(colpart, 32, 64);
  __shared__ float red[4][32];
  if (lane < 32) red[wave][lane] = colpart;
  __syncthreads();
  if (tid < 32) {
    float t = red[0][tid] + red[1][tid] + red[2][tid] + red[3][tid];
    rcp[(size_t)bh * S + kb + tid] = 1.0f / t;
  }
}

// Phase 2 v5 (tier-2, round-13 proven).
__global__ __launch_bounds__(256) void attn_out5_kernel(
    const unsigned short* __restrict__ qbf, const unsigned short* __restrict__ kbf,
    const unsigned short* __restrict__ vt, const unsigned* __restrict__ packed,
    const float* __restrict__ rcp, float* __restrict__ outp,
    float* __restrict__ attnp) {
  int tid = threadIdx.x;
  int wave = tid >> 6, lane = tid & 63;
  int l31 = lane & 31, hi = lane >> 5;
  int d0 = blockIdx.x;
  int xcd = d0 & 7, idx = d0 >> 3;
  int bh = xcd * 8 + (idx >> 3);
  int qblk = idx & 7;
  int qb = qblk * 128 + wave * 32;
  const float* rch = rcp + (size_t)bh * S;
  float* ah = attnp + (size_t)bh * S * S;
  const unsigned short* vtb = vt + (size_t)bh * D * S;
  const unsigned short* kbb = kbf + (size_t)bh * S * D;
  const unsigned* pmw = packed + ((size_t)bh * 32 + qblk * 4 + wave) * S;

  __shared__ unsigned short kst[2][32][72];
  __shared__ unsigned short vst[2][64][40];
  __shared__ unsigned short pt[4][32][132];

  int tr3 = tid >> 3, tc8 = tid & 7;
  int vr2 = tid >> 2, vc4 = tid & 3;

  short8 kreg = *(const short8*)(kbb + (size_t)tr3 * D + tc8 * 8);
  short8 vreg = *(const short8*)(vtb + (size_t)vr2 * S + vc4 * 8);
  unsigned mwcur = pmw[l31];
  short8 afrag[4];
  {
    const unsigned short* qp = qbf + ((size_t)bh * S + qb + l31) * D + hi * 8;
#pragma unroll
    for (int s = 0; s < 4; ++s) afrag[s] = *(const short8*)(qp + s * 16);
  }
  *(short8*)&kst[0][tr3][tc8 * 8] = kreg;
  *(short8*)&vst[0][vr2][vc4 * 8] = vreg;
  __syncthreads();

  f32x16 oacc0 = {}, oacc1 = {};

  for (int g = 0; g < 8; ++g) {
#pragma unroll
    for (int tg = 0; tg < 4; ++tg) {
      int kt = g * 4 + tg;
      int kb2 = kt * 32;
      const int cur = tg & 1;

      unsigned mwnxt = 0;
      if (kt < 31) {
        kreg = *(const short8*)(kbb + (size_t)(kb2 + 32 + tr3) * D + tc8 * 8);
        vreg = *(const short8*)(vtb + (size_t)vr2 * S + kb2 + 32 + vc4 * 8);
        mwnxt = pmw[kb2 + 32 + l31];
      }

      short8 bfrag[4];
#pragma unroll
      for (int s = 0; s < 4; ++s)
        bfrag[s] = *(const short8*)&kst[cur][l31][hi * 8 + s * 16];
      f32x16 acc = {};
#pragma unroll
      for (int s = 0; s < 4; ++s)
        acc = __builtin_amdgcn_mfma_f32_32x32x16_bf16(afrag[s], bfrag[s], acc, 0, 0, 0);

      short8 vA0 = *(const short8*)&vst[cur][l31][hi * 8];
      short8 vA1 = *(const short8*)&vst[cur][l31 + 32][hi * 8];
      short8 vB0 = *(const short8*)&vst[cur][l31][16 + hi * 8];
      short8 vB1 = *(const short8*)&vst[cur][l31 + 32][16 + hi * 8];

      float rc = rch[kb2 + l31];
#pragma unroll
      for (int r = 0; r < 16; ++r) {
        int ql = (r & 3) + 8 * (r >> 2) + 4 * hi;
        unsigned bit = (mwcur >> ql) & 1u;
        float e = bit ? __expf(acc[r] * SCALE) * rc : 0.0f;
        pt[wave][ql][tg * 32 + l31] = f2bf(e);
      }
      mwcur = mwnxt;

#pragma unroll
      for (int s2 = 0; s2 < 2; ++s2) {
        const unsigned short* pp = &pt[wave][l31][tg * 32 + s2 * 16 + hi * 8];
        s4v p0 = *(const s4v*)pp;
        s4v p1 = *(const s4v*)(pp + 4);
        short8 pa;
        pa[0] = p0[0]; pa[1] = p0[1]; pa[2] = p0[2]; pa[3] = p0[3];
        pa[4] = p1[0]; pa[5] = p1[1]; pa[6] = p1[2]; pa[7] = p1[3];
        oacc0 = __builtin_amdgcn_mfma_f32_32x32x16_bf16(pa, s2 ? vB0 : vA0, oacc0, 0, 0, 0);
        oacc1 = __builtin_amdgcn_mfma_f32_32x32x16_bf16(pa, s2 ? vB1 : vA1, oacc1, 0, 0, 0);
      }

      if (kt < 31) {
        *(short8*)&kst[cur ^ 1][tr3][tc8 * 8] = kreg;
        *(short8*)&vst[cur ^ 1][vr2][vc4 * 8] = vreg;
      }
      __syncthreads();
    }

#pragma unroll
    for (int it = 0; it < 8; ++it) {
      int row = it * 4 + (lane >> 4);
      int seg = lane & 15;
      const unsigned short* pp = &pt[wave][row][seg * 8];
      s4v a = *(const s4v*)pp;
      s4v b = *(const s4v*)(pp + 4);
      float4 f0, f1;
      f0.x = bf2f((unsigned short)a[0]); f0.y = bf2f((unsigned short)a[1]);
      f0.z = bf2f((unsigned short)a[2]); f0.w = bf2f((unsigned short)a[3]);
      f1.x = bf2f((unsigned short)b[0]); f1.y = bf2f((unsigned short)b[1]);
      f1.z = bf2f((unsigned short)b[2]); f1.w = bf2f((unsigned short)b[3]);
      float* dst = &ah[(size_t)(qb + row) * S + g * 128 + seg * 8];
      *(float4*)dst = f0;
      *(float4*)(dst + 4) = f1;
    }
  }

  float* oh = outp + (size_t)bh * S * D;
#pragma unroll
  for (int r = 0; r < 16; ++r) {
    int ql = (r & 3) + 8 * (r >> 2) + 4 * hi;
    oh[(size_t)(qb + ql) * D + l31] = oacc0[r];
    oh[(size_t)(qb + ql) * D + 32 + l31] = oacc1[r];
  }
}

// Fallback phase 2 (tiers 3/4).
template <bool PACKED>
__global__ __launch_bounds__(256) void attn_out_kernel(
    const float* __restrict__ q, const float* __restrict__ k,
    const float* __restrict__ v, const int* __restrict__ mask,
    const unsigned* __restrict__ packed, const float* __restrict__ rcp,
    float* __restrict__ outp, float* __restrict__ attnp) {
  int tid = threadIdx.x;
  int wave = tid >> 6, lane = tid & 63;
  int l31 = lane & 31, hi = lane >> 5;
  int bh = blockIdx.y;
  int qb = blockIdx.x * 128 + wave * 32;
  const int* mh = mask + (size_t)bh * S * S;
  const float* rch = rcp + (size_t)bh * S;
  float* ah = attnp + (size_t)bh * S * S;

  __shared__ float sm[4][32][33];
  __shared__ unsigned wlds[4][1024];

  if (PACKED) {
    const int4* src = (const int4*)(packed + ((size_t)bh * 32 + blockIdx.x * 4) * S);
    int4* dst = (int4*)&wlds[0][0];
#pragma unroll
    for (int j = 0; j < 4; ++j) dst[tid + j * 256] = src[tid + j * 256];
    __syncthreads();
  }

  short8 afrag[4];
  const float* qp = q + ((size_t)bh * S + qb + l31) * D + hi * 8;
#pragma unroll
  for (int s = 0; s < 4; ++s) afrag[s] = load_frag8_f32(qp + s * 16);

  f32x16 oacc0 = {}, oacc1 = {};

  for (int kt = 0; kt < 32; ++kt) {
    int kb2 = kt * 32;
    const float* kp = k + ((size_t)bh * S + kb2 + l31) * D + hi * 8;
    short8 bfrag[4];
#pragma unroll
    for (int s = 0; s < 4; ++s) bfrag[s] = load_frag8_f32(kp + s * 16);
    f32x16 acc = {};
#pragma unroll
    for (int s = 0; s < 4; ++s)
      acc = __builtin_amdgcn_mfma_f32_32x32x16_bf16(afrag[s], bfrag[s], acc, 0, 0, 0);

    int kcol = kb2 + l31;
    float rc = rch[kcol];
    unsigned mw = PACKED ? wlds[wave][kcol] : 0u;
#pragma unroll
    for (int r = 0; r < 16; ++r) {
      int ql = (r & 3) + 8 * (r >> 2) + 4 * hi;
      int qrow = qb + ql;
      unsigned bit;
      if (PACKED) bit = (mw >> ql) & 1u;
      else        bit = mh[(size_t)qrow * S + kcol] ? 1u : 0u;
      float e = bit ? __expf(acc[r] * SCALE) * rc : 0.0f;
      ah[(size_t)qrow * S + kcol] = e;
      sm[wave][ql][l31] = e;
    }
#pragma unroll
    for (int s2 = 0; s2 < 2; ++s2) {
      short8 pa;
      const float* smrow = &sm[wave][l31][0];
#pragma unroll
      for (int e = 0; e < 8; ++e) pa[e] = (short)f2bf(smrow[s2 * 16 + hi * 8 + e]);
      const float* vp = v + ((size_t)bh * S + kb2 + s2 * 16 + hi * 8) * D + l31;
      short8 vf0, vf1;
#pragma unroll
      for (int e = 0; e < 8; ++e) {
        vf0[e] = (short)f2bf(vp[(size_t)e * D]);
        vf1[e] = (short)f2bf(vp[(size_t)e * D + 32]);
      }
      oacc0 = __builtin_amdgcn_mfma_f32_32x32x16_bf16(pa, vf0, oacc0, 0, 0, 0);
      oacc1 = __builtin_amdgcn_mfma_f32_32x32x16_bf16(pa, vf1, oacc1, 0, 0, 0);
    }
  }

  float* oh = outp + (size_t)bh * S * D;
#pragma unroll
  for (int r = 0; r < 16; ++r) {
    int ql = (r & 3) + 8 * (r >> 2) + 4 * hi;
    oh[(size_t)(qb + ql) * D + l31] = oacc0[r];
    oh[(size_t)(qb + ql) * D + 32 + l31] = oacc1[r];
  }
}

extern "C" void kernel_launch(void* const* d_in, const int* in_sizes, int n_in,
                              void* d_out, int out_size, void* d_ws, size_t ws_size,
                              hipStream_t stream) {
  const float* q = (const float*)d_in[0];
  const float* k = (const float*)d_in[1];
  const float* v = (const float*)d_in[2];
  const int* mask = (const int*)d_in[3];
  float* outp = (float*)d_out;
  float* attnp = outp + (size_t)BH * S * D;  // out first, then attn
  float* rcp = (float*)d_ws;
  size_t rcp_bytes = (size_t)BH * S * 4;            // 256 KB
  size_t packed_bytes = (size_t)BH * 32 * S * 4;    // 8.4 MB
  size_t bf_bytes = (size_t)BH * S * D * 2;         // 8.4 MB each
  size_t partial_bytes = (size_t)BH * 32 * S * 4;   // 8.4 MB
  size_t outp1_bytes = (size_t)BH * S * D * 4;      // 16.8 MB

  unsigned* packed = (unsigned*)((char*)d_ws + rcp_bytes);
  unsigned short* qbf = (unsigned short*)((char*)d_ws + rcp_bytes + packed_bytes);
  unsigned short* kbf = qbf + (size_t)BH * S * D;
  unsigned short* vt = kbf + (size_t)BH * S * D;
  float* partial = (float*)(vt + (size_t)BH * S * D);
  float* outp1 = partial + (size_t)BH * 32 * S;

  size_t need_t2 = rcp_bytes + packed_bytes + 3 * bf_bytes + partial_bytes;
  size_t need_t1 = need_t2 + outp1_bytes;

  if (ws_size >= need_t1) {
    prep_kernel<<<dim3(1024, 3), 256, 0, stream>>>(q, k, v, qbf, kbf, vt);
    colsum2_kernel<<<512, 256, 0, stream>>>(qbf, kbf, mask, packed, partial);
    attn_out6_kernel<<<1024, 256, 0, stream>>>(qbf, kbf, vt, packed, partial,
                                               outp, outp1, attnp);
    combine_out_kernel<<<4096, 256, 0, stream>>>(outp1, outp);
  } else if (ws_size >= need_t2) {
    prep_kernel<<<dim3(1024, 3), 256, 0, stream>>>(q, k, v, qbf, kbf, vt);
    colsum2_kernel<<<512, 256, 0, stream>>>(qbf, kbf, mask, packed, partial);
    combine_kernel<<<256, 256, 0, stream>>>(partial, rcp);
    attn_out5_kernel<<<512, 256, 0, stream>>>(qbf, kbf, vt, packed, rcp, outp, attnp);
  } else if (ws_size >= rcp_bytes + packed_bytes) {
    colsum_kernel<true><<<2048, 256, 0, stream>>>(q, k, mask, rcp, packed);
    attn_out_kernel<true><<<dim3(S / 128, BH), 256, 0, stream>>>(
        q, k, v, mask, packed, rcp, outp, attnp);
  } else {
    colsum_kernel<false><<<2048, 256, 0, stream>>>(q, k, mask, rcp, nullptr);
    attn_out_kernel<false><<<dim3(S / 128, BH), 256, 0, stream>>>(
        q, k, v, mask, nullptr, rcp, outp, attnp);
  }
}